// Round 3
// baseline (99.288 us; speedup 1.0000x reference)
//
#include <hip/hip_runtime.h>

// LRFGraphConv: out[v] = ((nbr_sum[v] - deg[v]*verts[v]) @ lrf[v]) @ W^T + maxN*b
//
// R3: scan_accum was latency/redundancy-bound (redundancy = NB = 49 range
// blocks each rescanning the edges). VPB 1024 -> 4096 (64KB LDS, 2 blocks/CU)
// cuts redundancy to 13; 512-thread blocks give 16 waves/CU; NS=32 slices
// keep the grid at 416 blocks (~2/CU). Partials (NS*V float4 = 25.6MB) live
// in d_out, overwritten by the final projection kernel.

#define NS  32     // edge slices
#define VPB 4096   // vertices per range-block (LDS: VPB * 16B = 64KB)

__global__ __launch_bounds__(512)
void scan_accum(const float* __restrict__ verts,
                const int*   __restrict__ edges,
                float4* __restrict__ partial,   // [NS][V] (sumx,sumy,sumz,deg)
                int V, int E, int NB) {
    __shared__ float4 acc[VPB];
    int r = blockIdx.x % NB;   // vertex range
    int s = blockIdx.x / NB;   // edge slice
    int v0 = r * VPB;
    int nv = min(VPB, V - v0);

    for (int i = threadIdx.x; i < nv; i += blockDim.x)
        acc[i] = make_float4(0.f, 0.f, 0.f, 0.f);
    __syncthreads();

    int npairs = E >> 1;
    int p0 = (int)(((long long)npairs * s) / NS);
    int p1 = (int)(((long long)npairs * (s + 1)) / NS);
    const int4* e4 = (const int4*)edges;

    for (int p = p0 + threadIdx.x; p < p1; p += blockDim.x) {
        int4 e = e4[p];   // two undirected edges: (x,y) and (z,w)
        unsigned lx = (unsigned)(e.x - v0);
        unsigned ly = (unsigned)(e.y - v0);
        unsigned lz = (unsigned)(e.z - v0);
        unsigned lw = (unsigned)(e.w - v0);
        if (lx < (unsigned)nv) {          // center e.x accumulates neighbor e.y
            float* a = (float*)&acc[lx];
            atomicAdd(a + 0, verts[3 * e.y + 0]);
            atomicAdd(a + 1, verts[3 * e.y + 1]);
            atomicAdd(a + 2, verts[3 * e.y + 2]);
            atomicAdd(a + 3, 1.f);
        }
        if (ly < (unsigned)nv) {
            float* a = (float*)&acc[ly];
            atomicAdd(a + 0, verts[3 * e.x + 0]);
            atomicAdd(a + 1, verts[3 * e.x + 1]);
            atomicAdd(a + 2, verts[3 * e.x + 2]);
            atomicAdd(a + 3, 1.f);
        }
        if (lz < (unsigned)nv) {
            float* a = (float*)&acc[lz];
            atomicAdd(a + 0, verts[3 * e.w + 0]);
            atomicAdd(a + 1, verts[3 * e.w + 1]);
            atomicAdd(a + 2, verts[3 * e.w + 2]);
            atomicAdd(a + 3, 1.f);
        }
        if (lw < (unsigned)nv) {
            float* a = (float*)&acc[lw];
            atomicAdd(a + 0, verts[3 * e.z + 0]);
            atomicAdd(a + 1, verts[3 * e.z + 1]);
            atomicAdd(a + 2, verts[3 * e.z + 2]);
            atomicAdd(a + 3, 1.f);
        }
    }
    // odd trailing edge (E odd): handled once per range by slice NS-1
    if ((E & 1) && s == NS - 1 && threadIdx.x == 0) {
        int a = edges[2 * (E - 1) + 0];
        int b = edges[2 * (E - 1) + 1];
        unsigned la = (unsigned)(a - v0), lb = (unsigned)(b - v0);
        if (la < (unsigned)nv) {
            float* q = (float*)&acc[la];
            atomicAdd(q + 0, verts[3 * b + 0]);
            atomicAdd(q + 1, verts[3 * b + 1]);
            atomicAdd(q + 2, verts[3 * b + 2]);
            atomicAdd(q + 3, 1.f);
        }
        if (lb < (unsigned)nv) {
            float* q = (float*)&acc[lb];
            atomicAdd(q + 0, verts[3 * a + 0]);
            atomicAdd(q + 1, verts[3 * a + 1]);
            atomicAdd(q + 2, verts[3 * a + 2]);
            atomicAdd(q + 3, 1.f);
        }
    }
    __syncthreads();

    float4* dst = partial + (size_t)s * V + v0;
    for (int i = threadIdx.x; i < nv; i += blockDim.x)
        dst[i] = acc[i];
}

__global__ __launch_bounds__(256)
void reduce_nbr(const float4* __restrict__ partial,
                float4* __restrict__ nbrdeg,
                int* __restrict__ maxN, int V) {
    int v = blockIdx.x * blockDim.x + threadIdx.x;
    float4 acc = make_float4(0.f, 0.f, 0.f, 0.f);
    if (v < V) {
        #pragma unroll
        for (int s = 0; s < NS; ++s) {
            float4 p = partial[(size_t)s * V + v];
            acc.x += p.x; acc.y += p.y; acc.z += p.z; acc.w += p.w;
        }
        nbrdeg[v] = acc;
    }
    int m = (int)acc.w;
    #pragma unroll
    for (int off = 32; off > 0; off >>= 1)
        m = max(m, __shfl_down(m, off, 64));
    if ((threadIdx.x & 63) == 0) atomicMax(maxN, m);
}

__global__ __launch_bounds__(256)
void lrf_out(const float* __restrict__ verts,
             const float* __restrict__ lrf,
             const float4* __restrict__ W4,     // W as float4[96]
             const float4* __restrict__ bias4,  // bias as float4[32]
             const float4* __restrict__ nbrdeg,
             const int* __restrict__ maxN,
             float4* __restrict__ out4,         // out as float4[V*32]
             int V) {
    int t = blockIdx.x * blockDim.x + threadIdx.x;
    int v = t >> 5;        // vertex
    int q = t & 31;        // output quad: dims 4q..4q+3
    if (v >= V) return;

    float4 nd = nbrdeg[v];
    float s0 = nd.x - nd.w * verts[3 * v + 0];
    float s1 = nd.y - nd.w * verts[3 * v + 1];
    float s2 = nd.z - nd.w * verts[3 * v + 2];

    const float* L = lrf + (size_t)9 * v;   // lrf[v,j,k] row-major
    float r0 = s0 * L[0] + s1 * L[3] + s2 * L[6];
    float r1 = s0 * L[1] + s1 * L[4] + s2 * L[7];
    float r2 = s0 * L[2] + s1 * L[5] + s2 * L[8];

    float4 w0 = W4[3 * q + 0];
    float4 w1 = W4[3 * q + 1];
    float4 w2 = W4[3 * q + 2];
    float mx = (float)maxN[0];
    float4 bv = bias4[q];

    float4 o;
    o.x = r0 * w0.x + r1 * w0.y + r2 * w0.z + mx * bv.x;
    o.y = r0 * w0.w + r1 * w1.x + r2 * w1.y + mx * bv.y;
    o.z = r0 * w1.z + r1 * w1.w + r2 * w2.x + mx * bv.z;
    o.w = r0 * w2.y + r1 * w2.z + r2 * w2.w + mx * bv.w;
    out4[(size_t)v * 32 + q] = o;
}

extern "C" void kernel_launch(void* const* d_in, const int* in_sizes, int n_in,
                              void* d_out, int out_size, void* d_ws, size_t ws_size,
                              hipStream_t stream) {
    const float* verts = (const float*)d_in[0];
    const int*   edges = (const int*)d_in[1];
    const float* lrf   = (const float*)d_in[2];
    const float* W     = (const float*)d_in[3];
    const float* bias  = (const float*)d_in[4];

    int V = in_sizes[0] / 3;
    int E = in_sizes[1] / 2;
    int NB = (V + VPB - 1) / VPB;

    // ws layout: [maxN int][pad to 16B][nbrdeg: V float4]
    int* maxN = (int*)d_ws;
    float4* nbrdeg = (float4*)((char*)d_ws + 16);

    // per-slice partials live in d_out (NS*V*16B == out bytes for V=50k, D=128);
    // fully overwritten by lrf_out at the end of the same stream.
    float4* partial = (float4*)d_out;

    hipMemsetAsync(maxN, 0, 4, stream);

    scan_accum<<<NS * NB, 512, 0, stream>>>(verts, edges, partial, V, E, NB);

    int rb = (V + 255) / 256;
    reduce_nbr<<<rb, 256, 0, stream>>>(partial, nbrdeg, maxN, V);

    int ob = (V * 32 + 255) / 256;
    lrf_out<<<ob, 256, 0, stream>>>(verts, lrf, (const float4*)W,
                                    (const float4*)bias, nbrdeg, maxN,
                                    (float4*)d_out, V);
}

// Round 5
// 73.870 us; speedup vs baseline: 1.3441x; 1.3441x over previous
//
#include <hip/hip_runtime.h>
#include <hip/hip_fp16.h>

// LRFGraphConv: out[v] = ((nbr_sum[v] - deg[v]*verts[v]) @ lrf[v]) @ W^T + maxN*b
//
// R5 (= R4 + macro-hygiene fix): R2 structure (VPB=1024/16KB LDS, 256 thr ->
// 10 blocks/CU LDS cap) but NS=32 slices -> grid 1568 blocks (~24 waves/CU
// TLP; R2 had 12, R3 had 4). Partials stored as fp16x4 (8B) -> 12.8MB write +
// 12.8MB read. Edge loop 2x unrolled so two int4 loads are in flight before
// the branchy bodies.

#define NS  32     // edge slices
#define VPB 1024   // vertices per range-block (LDS: VPB * 16B = 16KB)

__device__ __forceinline__ ushort f2h(float f) {
    __half h = __float2half(f);
    return *(ushort*)&h;
}
__device__ __forceinline__ float h2f(ushort u) {
    __half h = *(__half*)&u;
    return __half2float(h);
}

#define PROCESS_EDGE(ex, ey)                                         \
    {                                                                \
        int _ec = (ex);                                              \
        int _en = (ey);                                              \
        unsigned _lc = (unsigned)(_ec - v0);                         \
        unsigned _ln = (unsigned)(_en - v0);                         \
        if (_lc < (unsigned)nv) {                                    \
            float* _accp = (float*)&acc[_lc];                        \
            atomicAdd(_accp + 0, verts[3 * _en + 0]);                \
            atomicAdd(_accp + 1, verts[3 * _en + 1]);                \
            atomicAdd(_accp + 2, verts[3 * _en + 2]);                \
            atomicAdd(_accp + 3, 1.f);                               \
        }                                                            \
        if (_ln < (unsigned)nv) {                                    \
            float* _accp = (float*)&acc[_ln];                        \
            atomicAdd(_accp + 0, verts[3 * _ec + 0]);                \
            atomicAdd(_accp + 1, verts[3 * _ec + 1]);                \
            atomicAdd(_accp + 2, verts[3 * _ec + 2]);                \
            atomicAdd(_accp + 3, 1.f);                               \
        }                                                            \
    }

__global__ __launch_bounds__(256)
void scan_accum(const float* __restrict__ verts,
                const int*   __restrict__ edges,
                ushort4* __restrict__ partial,   // [NS][V] fp16 (sx,sy,sz,deg)
                int V, int E, int NB) {
    __shared__ float4 acc[VPB];
    int r = blockIdx.x % NB;   // vertex range
    int s = blockIdx.x / NB;   // edge slice
    int v0 = r * VPB;
    int nv = min(VPB, V - v0);

    for (int i = threadIdx.x; i < nv; i += blockDim.x)
        acc[i] = make_float4(0.f, 0.f, 0.f, 0.f);
    __syncthreads();

    int npairs = E >> 1;
    int p0 = (int)(((long long)npairs * s) / NS);
    int p1 = (int)(((long long)npairs * (s + 1)) / NS);
    const int4* e4 = (const int4*)edges;

    int p = p0 + threadIdx.x;
    int step = blockDim.x;
    for (; p + step < p1; p += 2 * step) {
        int4 e1 = e4[p];
        int4 e2 = e4[p + step];
        PROCESS_EDGE(e1.x, e1.y)
        PROCESS_EDGE(e1.z, e1.w)
        PROCESS_EDGE(e2.x, e2.y)
        PROCESS_EDGE(e2.z, e2.w)
    }
    if (p < p1) {
        int4 e1 = e4[p];
        PROCESS_EDGE(e1.x, e1.y)
        PROCESS_EDGE(e1.z, e1.w)
    }
    // odd trailing edge (E odd): handled once per range by slice NS-1
    if ((E & 1) && s == NS - 1 && threadIdx.x == 0) {
        int ta = edges[2 * (E - 1) + 0];
        int tb = edges[2 * (E - 1) + 1];
        PROCESS_EDGE(ta, tb)
    }
    __syncthreads();

    ushort4* dst = partial + (size_t)s * V + v0;
    for (int i = threadIdx.x; i < nv; i += blockDim.x) {
        float4 a = acc[i];
        dst[i] = make_ushort4(f2h(a.x), f2h(a.y), f2h(a.z), f2h(a.w));
    }
}

__global__ __launch_bounds__(256)
void reduce_nbr(const ushort4* __restrict__ partial,
                float4* __restrict__ nbrdeg,
                int* __restrict__ maxN, int V) {
    int v = blockIdx.x * blockDim.x + threadIdx.x;
    float4 acc = make_float4(0.f, 0.f, 0.f, 0.f);
    if (v < V) {
        #pragma unroll
        for (int s = 0; s < NS; ++s) {
            ushort4 p = partial[(size_t)s * V + v];
            acc.x += h2f(p.x); acc.y += h2f(p.y);
            acc.z += h2f(p.z); acc.w += h2f(p.w);
        }
        nbrdeg[v] = acc;
    }
    int m = (int)acc.w;
    #pragma unroll
    for (int off = 32; off > 0; off >>= 1)
        m = max(m, __shfl_down(m, off, 64));
    if ((threadIdx.x & 63) == 0) atomicMax(maxN, m);
}

__global__ __launch_bounds__(256)
void lrf_out(const float* __restrict__ verts,
             const float* __restrict__ lrf,
             const float4* __restrict__ W4,     // W as float4[96]
             const float4* __restrict__ bias4,  // bias as float4[32]
             const float4* __restrict__ nbrdeg,
             const int* __restrict__ maxN,
             float4* __restrict__ out4,         // out as float4[V*32]
             int V) {
    int t = blockIdx.x * blockDim.x + threadIdx.x;
    int v = t >> 5;        // vertex
    int q = t & 31;        // output quad: dims 4q..4q+3
    if (v >= V) return;

    float4 nd = nbrdeg[v];
    float s0 = nd.x - nd.w * verts[3 * v + 0];
    float s1 = nd.y - nd.w * verts[3 * v + 1];
    float s2 = nd.z - nd.w * verts[3 * v + 2];

    const float* L = lrf + (size_t)9 * v;   // lrf[v,j,k] row-major
    float r0 = s0 * L[0] + s1 * L[3] + s2 * L[6];
    float r1 = s0 * L[1] + s1 * L[4] + s2 * L[7];
    float r2 = s0 * L[2] + s1 * L[5] + s2 * L[8];

    float4 w0 = W4[3 * q + 0];
    float4 w1 = W4[3 * q + 1];
    float4 w2 = W4[3 * q + 2];
    float mx = (float)maxN[0];
    float4 bv = bias4[q];

    float4 o;
    o.x = r0 * w0.x + r1 * w0.y + r2 * w0.z + mx * bv.x;
    o.y = r0 * w0.w + r1 * w1.x + r2 * w1.y + mx * bv.y;
    o.z = r0 * w1.z + r1 * w1.w + r2 * w2.x + mx * bv.z;
    o.w = r0 * w2.y + r1 * w2.z + r2 * w2.w + mx * bv.w;
    out4[(size_t)v * 32 + q] = o;
}

extern "C" void kernel_launch(void* const* d_in, const int* in_sizes, int n_in,
                              void* d_out, int out_size, void* d_ws, size_t ws_size,
                              hipStream_t stream) {
    const float* verts = (const float*)d_in[0];
    const int*   edges = (const int*)d_in[1];
    const float* lrf   = (const float*)d_in[2];
    const float* W     = (const float*)d_in[3];
    const float* bias  = (const float*)d_in[4];

    int V = in_sizes[0] / 3;
    int E = in_sizes[1] / 2;
    int NB = (V + VPB - 1) / VPB;

    // ws layout: [maxN int][pad to 16B][nbrdeg: V float4]
    int* maxN = (int*)d_ws;
    float4* nbrdeg = (float4*)((char*)d_ws + 16);

    // per-slice fp16 partials live in d_out (NS*V*8B = 12.8MB < 25.6MB);
    // fully overwritten by lrf_out at the end of the same stream.
    ushort4* partial = (ushort4*)d_out;

    (void)hipMemsetAsync(maxN, 0, 4, stream);

    scan_accum<<<NS * NB, 256, 0, stream>>>(verts, edges, partial, V, E, NB);

    int rb = (V + 255) / 256;
    reduce_nbr<<<rb, 256, 0, stream>>>(partial, nbrdeg, maxN, V);

    int ob = (V * 32 + 255) / 256;
    lrf_out<<<ob, 256, 0, stream>>>(verts, lrf, (const float4*)W,
                                    (const float4*)bias, nbrdeg, maxN,
                                    (float4*)d_out, V);
}